// Round 6
// baseline (16.389 us; speedup 1.0000x reference)
//
#include <hip/hip_runtime.h>

// Problem constants (from reference): B=8, A=9, H=56, W=56, N=64
#define BB 8
#define AA 9
#define HH 56
#define WW 56
#define NN 64

constexpr int P   = AA * HH * WW;  // 28224 = 441 * 64 proposals per batch image
constexpr int HW  = HH * WW;       // 3136
constexpr int BLK = 64;            // one wave per block; 64 proposals per block
constexpr int PBLK = P / BLK;      // 441 blocks per batch image, NO tail

// clang-native vector type: __builtin_nontemporal_store accepts these
// (it rejects HIP_vector_type<float,4>).
typedef float f32x4 __attribute__((ext_vector_type(4)));

// Fused proposals + IoU, single-wave blocks, zero tail, barrier-free:
// Phase 1: each of 64 threads computes 1 proposal -> LDS + global (NT float4).
// Phase 2: wave-local. Each thread owns 4 bboxes in registers (n4 = tid&15),
//          sub = tid>>4 selects proposal within each of 16 fully-unrolled
//          iterations; one coalesced NT float4 store per iteration
//          (1 KB/wave contiguous).
__global__ __launch_bounds__(BLK) void fused_detector_kernel(
    const float* __restrict__ anc,      // (9,2)
    const float* __restrict__ grid,     // (8,56,56,2)
    const float* __restrict__ offsets,  // (8,9,56,56,4)
    const float* __restrict__ bboxes,   // (8,64,5)
    float* __restrict__ out_prop,       // (8,9,56,56,4)
    float* __restrict__ out_iou)        // (8,28224,64)
{
    __shared__ f32x4 sprop[BLK];

    const int tid = threadIdx.x;       // 0..63
    const int b   = blockIdx.y;
    const int p0  = blockIdx.x * BLK;
    const int p   = p0 + tid;          // always < P (no tail)

    // ---- issue the long-latency offsets load FIRST ----
    f32x4 off = reinterpret_cast<const f32x4*>(offsets)[(size_t)b * P + p];

    // ---- bbox prefetch into registers ----
    const int n4 = tid & 15;           // this thread's bbox group, fixed
    float bx0[4], by0[4], bx1[4], by1[4], bar[4];
    #pragma unroll
    for (int i = 0; i < 4; ++i) {
        const float* bb = bboxes + (size_t)(b * NN + n4 * 4 + i) * 5;
        bx0[i] = bb[0]; by0[i] = bb[1]; bx1[i] = bb[2]; by1[i] = bb[3];
        bar[i] = (bx1[i] - bx0[i]) * (by1[i] - by0[i]);
    }

    // ---- phase 1: proposal ----
    {
        int a  = p / HW;
        int hw = p - a * HW;
        float2 g  = reinterpret_cast<const float2*>(grid)[b * HW + hw];
        float  aw = anc[a * 2 + 0];
        float  ah = anc[a * 2 + 1];

        float cx = g.x + off.x;
        float cy = g.y + off.y;
        float pw = aw * __expf(off.z);
        float ph = ah * __expf(off.w);

        f32x4 pr;
        pr.x = cx - 0.5f * pw;
        pr.y = cy - 0.5f * ph;
        pr.z = cx + 0.5f * pw;
        pr.w = cy + 0.5f * ph;

        sprop[tid] = pr;
        __builtin_nontemporal_store(pr, reinterpret_cast<f32x4*>(out_prop) + (size_t)b * P + p);
    }
    // No barrier: single-wave block, LDS ordering via lgkmcnt.

    // ---- phase 2: IoU ----
    const int sub = tid >> 4;          // proposal sub-index (0..3)
    f32x4* iou4 = reinterpret_cast<f32x4*>(out_iou) + ((size_t)b * P + p0) * (NN / 4);

    #pragma unroll
    for (int c = 0; c < 16; ++c) {
        const int pl = c * 4 + sub;
        f32x4 pr = sprop[pl];
        float pa = (pr.z - pr.x) * (pr.w - pr.y);

        float rv[4];
        #pragma unroll
        for (int i = 0; i < 4; ++i) {
            float mx0 = fmaxf(pr.x, bx0[i]);
            float my0 = fmaxf(pr.y, by0[i]);
            float mn1 = fminf(pr.z, bx1[i]);
            float mn2 = fminf(pr.w, by1[i]);
            float iw  = fmaxf(mn1 - mx0, 0.0f);
            float ih  = fmaxf(mn2 - my0, 0.0f);
            float inter = iw * ih;
            float uni   = pa + bar[i] - inter;
            rv[i] = inter * __builtin_amdgcn_rcpf(uni);
        }
        f32x4 r;
        r.x = rv[0]; r.y = rv[1]; r.z = rv[2]; r.w = rv[3];
        __builtin_nontemporal_store(r, iou4 + (size_t)pl * (NN / 4) + n4);
    }
}

extern "C" void kernel_launch(void* const* d_in, const int* in_sizes, int n_in,
                              void* d_out, int out_size, void* d_ws, size_t ws_size,
                              hipStream_t stream) {
    const float* anc     = (const float*)d_in[0];  // (9, 2)
    const float* grid    = (const float*)d_in[1];  // (8, 56, 56, 2)
    const float* offsets = (const float*)d_in[2];  // (8, 9, 56, 56, 4)
    const float* bboxes  = (const float*)d_in[3];  // (8, 64, 5)

    float* out_proposals = (float*)d_out;                        // 903168 floats
    float* out_iou       = (float*)d_out + (size_t)BB * P * 4;   // 14450688 floats

    dim3 gridsz(PBLK, BB);
    fused_detector_kernel<<<gridsz, BLK, 0, stream>>>(
        anc, grid, offsets, bboxes, out_proposals, out_iou);
}